// Round 2
// baseline (202.620 us; speedup 1.0000x reference)
//
#include <hip/hip_runtime.h>

#define DEVINL __device__ __forceinline__

// ---------------------------------------------------------------------------
// Graph structure (compile-time), derived from the reference _build_graph():
//   SUBSETS = [[0,5,6,11,12],[7,8,13,14],[9,10,15,16]]
//   PHYS[i] = complete graph on subset i  =>  H_u = msum - m_u on subset, 0 off.
//   feat==0 outside subset i  =>  cross-neighbor c==0, other-side a==be.
//   msg = relu((We1-We2)Â·feat_j + We2Â·feat_k + be) = relu(a_j + c_k).
//   OTH = # other-side joints adjacent to subset i (their Z = max_k relu(be+c_k);
//   non-adjacent joints have empty neighbor lists => Z = 0):
//   level0: |s1|=4, level1: |s0|+|s2|=9, level2: |s1|=4.
// ---------------------------------------------------------------------------

template <int LI, int CNT, int OTH>
DEVINL void do_level(int w, int lane,
                     const float* __restrict__ Wl, const float* __restrict__ bl,
                     float mnx, float ix, float mny, float iy,
                     const float (*Praw)[17][3],
                     float (*featS)[64][8],
                     const float2 (*WW)[64],
                     const float* beS,
                     float (*finS)[384]) {
    constexpr int SUBJ[3][5] = {{0, 5, 6, 11, 12}, {7, 8, 13, 14, 16}, {9, 10, 15, 16, 16}};

    // per-channel weights of the level-input MLP (W: [64][3], b: [64])
    float w0 = Wl[lane * 3 + 0];
    float w1 = Wl[lane * 3 + 1];
    float w2 = Wl[lane * 3 + 2];
    float bb = bl[lane];

    float mj[CNT], sj[CNT];
    float msum = 0.f;
#pragma unroll
    for (int jj = 0; jj < CNT; ++jj) {
        int j = SUBJ[LI][jj];
        float px = (Praw[w][j][0] - mnx) * ix;
        float py = (Praw[w][j][1] - mny) * iy;
        float ps = Praw[w][j][2];
        float h = fmaxf(px * w0 + py * w1 + ps * w2 + bb, 0.f);
        float m = h * ps;
        mj[jj] = m;
        sj[jj] = ps;
        msum += m;
    }
    // H_j = msum - m_j  (complete graph), feat_j = H_j * s_j
#pragma unroll
    for (int jj = 0; jj < CNT; ++jj) {
        featS[w][lane][jj] = (msum - mj[jj]) * sj[jj];
    }
    float Hsum = (float)(CNT - 1) * msum;  // sum over subset of H_j
    __syncthreads();

    // a_j[t] = sum_d (We1-We2)[t][d] * feat_j[d] + be[t]
    // c_j[t] = sum_d  We2[t][d]      * feat_j[d]
    float a_[CNT], c_[CNT];
    float bet = beS[lane];
#pragma unroll
    for (int jj = 0; jj < CNT; ++jj) { a_[jj] = bet; c_[jj] = 0.f; }
#pragma unroll 4
    for (int d = 0; d < 64; ++d) {
        float2 wv = WW[d][lane];                      // {We1-We2, We2}[d][t]
        const float* fr = &featS[w][d][0];            // broadcast reads
        float4 f4 = *(const float4*)fr;
        float f[5];
        f[0] = f4.x; f[1] = f4.y; f[2] = f4.z; f[3] = f4.w; f[4] = 0.f;
        if constexpr (CNT > 4) f[4] = fr[4];
#pragma unroll
        for (int jj = 0; jj < CNT; ++jj) {
            a_[jj] = fmaf(wv.x, f[jj], a_[jj]);
            c_[jj] = fmaf(wv.y, f[jj], c_[jj]);
        }
    }
    __syncthreads();

    // Z_j = max( relu(a_j), max_{k in subset, k!=j} relu(a_j + c_k) )
    float zsum = 0.f;
#pragma unroll
    for (int jj = 0; jj < CNT; ++jj) {
        float z = fmaxf(a_[jj], 0.f);  // cross-level neighbors: c = 0
#pragma unroll
        for (int kk = 0; kk < CNT; ++kk) {
            if (kk != jj) z = fmaxf(z, a_[jj] + c_[kk]);  // relu folded (z>=0)
        }
        zsum += z;
    }
    // other-side joints adjacent to this subset all share Zoth = max_k relu(be+c_k)
    float zo = 0.f;
#pragma unroll
    for (int kk = 0; kk < CNT; ++kk) zo = fmaxf(zo, bet + c_[kk]);
    zsum += (float)OTH * zo;

    finS[w][LI * 128 + lane] = Hsum * (1.f / 17.f);
    finS[w][LI * 128 + 64 + lane] = zsum * (1.f / 17.f);
}

__global__ __launch_bounds__(256) void hse_kernel(
    const float* __restrict__ kp, const float* __restrict__ sc,
    const float* __restrict__ W0, const float* __restrict__ b0,
    const float* __restrict__ W1, const float* __restrict__ b1,
    const float* __restrict__ W2, const float* __restrict__ b2,
    const float* __restrict__ We, const float* __restrict__ be,
    const float* __restrict__ Wp, const float* __restrict__ bp,
    float* __restrict__ out) {
    __shared__ float2 WW[64][64];      // [d][t] = {We1-We2, We2}
    __shared__ float beS[64];
    __shared__ float Praw[4][17][3];   // [wave][joint][{x,y,s}]
    __shared__ float featS[4][64][8];  // [wave][channel d][jj] (padded)
    __shared__ float finS[4][384];     // [wave][final feature]

    int tid = threadIdx.x;
    int w = tid >> 6;
    int lane = tid & 63;
    int sample = blockIdx.x * 4 + w;

    // ---- stage We-derived matrices (once per block) ----
    for (int i = tid; i < 4096; i += 256) {
        int t = i >> 6, d = i & 63;
        float wA = We[t * 128 + d];
        float wB = We[t * 128 + 64 + d];
        WW[d][t] = make_float2(wA - wB, wB);
    }
    if (tid < 64) beS[tid] = be[tid];

    // ---- stage raw keypoints/scores for this wave's sample ----
    if (lane < 17) {
        size_t base = (size_t)sample * 17 + lane;
        float2 xy = *(const float2*)(kp + base * 2);
        Praw[w][lane][0] = xy.x;
        Praw[w][lane][1] = xy.y;
        Praw[w][lane][2] = sc[base];
    }
    __syncthreads();

    // per-coordinate min/max over 17 joints (all lanes, broadcast LDS reads)
    float mnx = 1e30f, mxx = -1e30f, mny = 1e30f, mxy = -1e30f;
    for (int j = 0; j < 17; ++j) {
        float x = Praw[w][j][0], y = Praw[w][j][1];
        mnx = fminf(mnx, x); mxx = fmaxf(mxx, x);
        mny = fminf(mny, y); mxy = fmaxf(mxy, y);
    }
    float ix = 1.f / (mxx - mnx + 1e-6f);
    float iy = 1.f / (mxy - mny + 1e-6f);

    do_level<0, 5, 4>(w, lane, W0, b0, mnx, ix, mny, iy, Praw, featS, WW, beS, finS);
    do_level<1, 4, 9>(w, lane, W1, b1, mnx, ix, mny, iy, Praw, featS, WW, beS, finS);
    do_level<2, 4, 4>(w, lane, W2, b2, mnx, ix, mny, iy, Praw, featS, WW, beS, finS);

    __syncthreads();

    // ---- output GEMV: out[o] = sum_e final[e] * Wp[o][e] + bp[o] ----
    float acc0 = bp[lane];
    float acc1 = bp[64 + lane];
    const float* r0 = Wp + (size_t)lane * 384;
    const float* r1 = Wp + (size_t)(64 + lane) * 384;
    const float* fv = finS[w];
#pragma unroll 8
    for (int e = 0; e < 384; e += 4) {
        float4 wa = *(const float4*)(r0 + e);
        float4 wb = *(const float4*)(r1 + e);
        float4 f = *(const float4*)(fv + e);
        acc0 = fmaf(wa.x, f.x, acc0);
        acc0 = fmaf(wa.y, f.y, acc0);
        acc0 = fmaf(wa.z, f.z, acc0);
        acc0 = fmaf(wa.w, f.w, acc0);
        acc1 = fmaf(wb.x, f.x, acc1);
        acc1 = fmaf(wb.y, f.y, acc1);
        acc1 = fmaf(wb.z, f.z, acc1);
        acc1 = fmaf(wb.w, f.w, acc1);
    }
    out[(size_t)sample * 128 + lane] = acc0;
    out[(size_t)sample * 128 + 64 + lane] = acc1;
}

extern "C" void kernel_launch(void* const* d_in, const int* in_sizes, int n_in,
                              void* d_out, int out_size, void* d_ws, size_t ws_size,
                              hipStream_t stream) {
    const float* kp = (const float*)d_in[0];
    const float* sc = (const float*)d_in[1];
    const float* W0 = (const float*)d_in[2];
    const float* b0 = (const float*)d_in[3];
    const float* W1 = (const float*)d_in[4];
    const float* b1 = (const float*)d_in[5];
    const float* W2 = (const float*)d_in[6];
    const float* b2 = (const float*)d_in[7];
    const float* We = (const float*)d_in[8];
    const float* be = (const float*)d_in[9];
    const float* Wp = (const float*)d_in[10];
    const float* bp = (const float*)d_in[11];
    float* out = (float*)d_out;

    int N = in_sizes[1] / 17;  // 8192
    dim3 grid(N / 4), block(256);
    hipLaunchKernelGGL(hse_kernel, grid, block, 0, stream,
                       kp, sc, W0, b0, W1, b1, W2, b2, We, be, Wp, bp, out);
}

// Round 3
// 72.748 us; speedup vs baseline: 2.7852x; 2.7852x over previous
//
#include <hip/hip_runtime.h>

#define DEVINL __device__ __forceinline__

// ===========================================================================
// K1: per-sample graph encoder. 8 waves/block, 1 sample/wave.
// Writes final[sample][384] features to workspace.
//
// Algebra (validated round 2): PHYS = complete graph per subset =>
// H_u = msum - m_u; edge MLP msg = relu(a_j + c_k) with
// a_j = (We1-We2)·feat_j + be, c_k = We2·feat_k; feat==0 off-subset =>
// cross-level c==0, other-side a==be; OTH adjacent other-side joints share
// Zoth = max_k relu(be + c_k); non-adjacent joints Z = 0.
// ===========================================================================

template <int LI, int CNT, int OTH>
DEVINL void do_level(int w, int lane,
                     const float* __restrict__ Wl, const float* __restrict__ bl,
                     float mnx, float ix, float mny, float iy,
                     const float (*Praw)[17][3],
                     float (*featS)[64][8],
                     const float2 (*WW)[64],
                     const float* beS,
                     float* __restrict__ outv) {
    constexpr int SUBJ[3][5] = {{0, 5, 6, 11, 12}, {7, 8, 13, 14, 16}, {9, 10, 15, 16, 16}};

    float w0 = Wl[lane * 3 + 0];
    float w1 = Wl[lane * 3 + 1];
    float w2 = Wl[lane * 3 + 2];
    float bb = bl[lane];

    float mj[CNT], sj[CNT];
    float msum = 0.f;
#pragma unroll
    for (int jj = 0; jj < CNT; ++jj) {
        int j = SUBJ[LI][jj];
        float px = (Praw[w][j][0] - mnx) * ix;
        float py = (Praw[w][j][1] - mny) * iy;
        float ps = Praw[w][j][2];
        float h = fmaxf(px * w0 + py * w1 + ps * w2 + bb, 0.f);
        float m = h * ps;
        mj[jj] = m;
        sj[jj] = ps;
        msum += m;
    }
#pragma unroll
    for (int jj = 0; jj < CNT; ++jj) {
        featS[w][lane][jj] = (msum - mj[jj]) * sj[jj];
    }
    float Hsum = (float)(CNT - 1) * msum;
    __syncthreads();

    // a_j[t] = (We1-We2)·feat_j + be ; c_j[t] = We2·feat_j  (t = lane)
    float a_[CNT], c_[CNT];
    float bet = beS[lane];
#pragma unroll
    for (int jj = 0; jj < CNT; ++jj) { a_[jj] = bet; c_[jj] = 0.f; }
#pragma unroll 4
    for (int d = 0; d < 64; ++d) {
        float2 wv = WW[d][lane ^ d];                  // XOR-swizzled columns
        const float* fr = &featS[w][d][0];            // broadcast reads
        float4 f4 = *(const float4*)fr;
        float f[5];
        f[0] = f4.x; f[1] = f4.y; f[2] = f4.z; f[3] = f4.w; f[4] = 0.f;
        if constexpr (CNT > 4) f[4] = fr[4];
#pragma unroll
        for (int jj = 0; jj < CNT; ++jj) {
            a_[jj] = fmaf(wv.x, f[jj], a_[jj]);
            c_[jj] = fmaf(wv.y, f[jj], c_[jj]);
        }
    }
    __syncthreads();

    float zsum = 0.f;
#pragma unroll
    for (int jj = 0; jj < CNT; ++jj) {
        float z = fmaxf(a_[jj], 0.f);
#pragma unroll
        for (int kk = 0; kk < CNT; ++kk) {
            if (kk != jj) z = fmaxf(z, a_[jj] + c_[kk]);
        }
        zsum += z;
    }
    float zo = 0.f;
#pragma unroll
    for (int kk = 0; kk < CNT; ++kk) zo = fmaxf(zo, bet + c_[kk]);
    zsum += (float)OTH * zo;

    outv[LI * 128 + lane] = Hsum * (1.f / 17.f);
    outv[LI * 128 + 64 + lane] = zsum * (1.f / 17.f);
}

__global__ __launch_bounds__(512, 6) void graph_kernel(
    const float* __restrict__ kp, const float* __restrict__ sc,
    const float* __restrict__ W0, const float* __restrict__ b0,
    const float* __restrict__ W1, const float* __restrict__ b1,
    const float* __restrict__ W2, const float* __restrict__ b2,
    const float* __restrict__ We, const float* __restrict__ be,
    float* __restrict__ fout) {
    __shared__ float2 WW[64][64];      // [d][t^d] = {We1-We2, We2}
    __shared__ float beS[64];
    __shared__ float Praw[8][17][3];
    __shared__ float featS[8][64][8];

    int tid = threadIdx.x;
    int w = tid >> 6;
    int lane = tid & 63;
    int sample = blockIdx.x * 8 + w;

    // stage WW with XOR-swizzled column: store (d,t) at [d][t^d].
    // staging lanes have d=lane, t uniform -> banks spread across all 32.
    for (int i = tid; i < 4096; i += 512) {
        int t = i >> 6, d = i & 63;
        float wA = We[t * 128 + d];
        float wB = We[t * 128 + 64 + d];
        WW[d][t ^ d] = make_float2(wA - wB, wB);
    }
    if (tid < 64) beS[tid] = be[tid];

    if (lane < 17) {
        size_t base = (size_t)sample * 17 + lane;
        float2 xy = *(const float2*)(kp + base * 2);
        Praw[w][lane][0] = xy.x;
        Praw[w][lane][1] = xy.y;
        Praw[w][lane][2] = sc[base];
    }
    __syncthreads();

    // min/max over 17 joints via 32-wide shuffle butterfly (lanes 32..63
    // mirror lanes 0..31, neutrals beyond joint 16)
    int j = lane & 31;
    float xx = 0.f, yy = 0.f;
    if (j < 17) { xx = Praw[w][j][0]; yy = Praw[w][j][1]; }
    float mnx = (j < 17) ? xx : 1e30f, mxx = (j < 17) ? xx : -1e30f;
    float mny = (j < 17) ? yy : 1e30f, mxy = (j < 17) ? yy : -1e30f;
#pragma unroll
    for (int off = 16; off; off >>= 1) {
        mnx = fminf(mnx, __shfl_xor(mnx, off, 32));
        mxx = fmaxf(mxx, __shfl_xor(mxx, off, 32));
        mny = fminf(mny, __shfl_xor(mny, off, 32));
        mxy = fmaxf(mxy, __shfl_xor(mxy, off, 32));
    }
    float ix = 1.f / (mxx - mnx + 1e-6f);
    float iy = 1.f / (mxy - mny + 1e-6f);

    float* outv = fout + (size_t)sample * 384;
    do_level<0, 5, 4>(w, lane, W0, b0, mnx, ix, mny, iy, Praw, featS, WW, beS, outv);
    do_level<1, 4, 9>(w, lane, W1, b1, mnx, ix, mny, iy, Praw, featS, WW, beS, outv);
    do_level<2, 4, 4>(w, lane, W2, b2, mnx, ix, mny, iy, Praw, featS, WW, beS, outv);
}

// ===========================================================================
// K2: out[8192][128] = final[8192][384] @ Wp^T + bp.  Tiled fp32 GEMM.
// BM=32 samples, BN=128 outs, BK=64. 512 threads; 8 acc/thread (2s x 4o).
// ===========================================================================
__global__ __launch_bounds__(512) void out_gemm_kernel(
    const float* __restrict__ fin, const float* __restrict__ Wp,
    const float* __restrict__ bp, float* __restrict__ out) {
    __shared__ float Atile[64][34];   // [k][s], pad 2
    __shared__ float Btile[64][132];  // [k][o], pad 4 (rows 16B-aligned)

    int tid = threadIdx.x;
    int sB = blockIdx.x * 32;
    int og = tid & 31;        // 4 outputs: og*4 ..
    int sg = tid >> 5;        // 2 samples: sg*2 ..
    int o0 = og * 4;
    int s0 = sg * 2;

    float4 bias = *(const float4*)(bp + o0);
    float4 acc0 = bias, acc1 = bias;

    for (int kt = 0; kt < 384; kt += 64) {
        // stage A: 32x64, coalesced along k
#pragma unroll
        for (int r = 0; r < 4; ++r) {
            int i = r * 512 + tid;
            int ks = i & 63, ss = i >> 6;
            Atile[ks][ss] = fin[(size_t)(sB + ss) * 384 + kt + ks];
        }
        // stage B: 128x64, coalesced along k
#pragma unroll
        for (int r = 0; r < 16; ++r) {
            int i = r * 512 + tid;
            int ks = i & 63, os = i >> 6;
            Btile[ks][os] = Wp[(size_t)os * 384 + kt + ks];
        }
        __syncthreads();

#pragma unroll 4
        for (int k = 0; k < 64; ++k) {
            float2 a = *(const float2*)&Atile[k][s0];
            float4 b = *(const float4*)&Btile[k][o0];
            acc0.x = fmaf(a.x, b.x, acc0.x);
            acc0.y = fmaf(a.x, b.y, acc0.y);
            acc0.z = fmaf(a.x, b.z, acc0.z);
            acc0.w = fmaf(a.x, b.w, acc0.w);
            acc1.x = fmaf(a.y, b.x, acc1.x);
            acc1.y = fmaf(a.y, b.y, acc1.y);
            acc1.z = fmaf(a.y, b.z, acc1.z);
            acc1.w = fmaf(a.y, b.w, acc1.w);
        }
        __syncthreads();
    }

    *(float4*)(out + (size_t)(sB + s0) * 128 + o0) = acc0;
    *(float4*)(out + (size_t)(sB + s0 + 1) * 128 + o0) = acc1;
}

// ===========================================================================
// Fallback: validated round-2 fused kernel (used only if ws too small).
// ===========================================================================
template <int LI, int CNT, int OTH>
DEVINL void do_level_f(int w, int lane,
                       const float* __restrict__ Wl, const float* __restrict__ bl,
                       float mnx, float ix, float mny, float iy,
                       const float (*Praw)[17][3],
                       float (*featS)[64][8],
                       const float2 (*WW)[64],
                       const float* beS,
                       float (*finS)[384]) {
    constexpr int SUBJ[3][5] = {{0, 5, 6, 11, 12}, {7, 8, 13, 14, 16}, {9, 10, 15, 16, 16}};
    float w0 = Wl[lane * 3 + 0], w1 = Wl[lane * 3 + 1], w2 = Wl[lane * 3 + 2], bb = bl[lane];
    float mj[CNT], sj[CNT];
    float msum = 0.f;
#pragma unroll
    for (int jj = 0; jj < CNT; ++jj) {
        int j = SUBJ[LI][jj];
        float px = (Praw[w][j][0] - mnx) * ix;
        float py = (Praw[w][j][1] - mny) * iy;
        float ps = Praw[w][j][2];
        float h = fmaxf(px * w0 + py * w1 + ps * w2 + bb, 0.f);
        float m = h * ps;
        mj[jj] = m; sj[jj] = ps; msum += m;
    }
#pragma unroll
    for (int jj = 0; jj < CNT; ++jj) featS[w][lane][jj] = (msum - mj[jj]) * sj[jj];
    float Hsum = (float)(CNT - 1) * msum;
    __syncthreads();
    float a_[CNT], c_[CNT];
    float bet = beS[lane];
#pragma unroll
    for (int jj = 0; jj < CNT; ++jj) { a_[jj] = bet; c_[jj] = 0.f; }
#pragma unroll 4
    for (int d = 0; d < 64; ++d) {
        float2 wv = WW[d][lane];
        const float* fr = &featS[w][d][0];
        float4 f4 = *(const float4*)fr;
        float f[5];
        f[0] = f4.x; f[1] = f4.y; f[2] = f4.z; f[3] = f4.w; f[4] = 0.f;
        if constexpr (CNT > 4) f[4] = fr[4];
#pragma unroll
        for (int jj = 0; jj < CNT; ++jj) {
            a_[jj] = fmaf(wv.x, f[jj], a_[jj]);
            c_[jj] = fmaf(wv.y, f[jj], c_[jj]);
        }
    }
    __syncthreads();
    float zsum = 0.f;
#pragma unroll
    for (int jj = 0; jj < CNT; ++jj) {
        float z = fmaxf(a_[jj], 0.f);
#pragma unroll
        for (int kk = 0; kk < CNT; ++kk)
            if (kk != jj) z = fmaxf(z, a_[jj] + c_[kk]);
        zsum += z;
    }
    float zo = 0.f;
#pragma unroll
    for (int kk = 0; kk < CNT; ++kk) zo = fmaxf(zo, bet + c_[kk]);
    zsum += (float)OTH * zo;
    finS[w][LI * 128 + lane] = Hsum * (1.f / 17.f);
    finS[w][LI * 128 + 64 + lane] = zsum * (1.f / 17.f);
}

__global__ __launch_bounds__(256) void hse_fused_kernel(
    const float* __restrict__ kp, const float* __restrict__ sc,
    const float* __restrict__ W0, const float* __restrict__ b0,
    const float* __restrict__ W1, const float* __restrict__ b1,
    const float* __restrict__ W2, const float* __restrict__ b2,
    const float* __restrict__ We, const float* __restrict__ be,
    const float* __restrict__ Wp, const float* __restrict__ bp,
    float* __restrict__ out) {
    __shared__ float2 WW[64][64];
    __shared__ float beS[64];
    __shared__ float Praw[4][17][3];
    __shared__ float featS[4][64][8];
    __shared__ float finS[4][384];

    int tid = threadIdx.x;
    int w = tid >> 6;
    int lane = tid & 63;
    int sample = blockIdx.x * 4 + w;

    for (int i = tid; i < 4096; i += 256) {
        int t = i >> 6, d = i & 63;
        float wA = We[t * 128 + d];
        float wB = We[t * 128 + 64 + d];
        WW[d][t] = make_float2(wA - wB, wB);
    }
    if (tid < 64) beS[tid] = be[tid];
    if (lane < 17) {
        size_t base = (size_t)sample * 17 + lane;
        float2 xy = *(const float2*)(kp + base * 2);
        Praw[w][lane][0] = xy.x;
        Praw[w][lane][1] = xy.y;
        Praw[w][lane][2] = sc[base];
    }
    __syncthreads();

    float mnx = 1e30f, mxx = -1e30f, mny = 1e30f, mxy = -1e30f;
    for (int j = 0; j < 17; ++j) {
        float x = Praw[w][j][0], y = Praw[w][j][1];
        mnx = fminf(mnx, x); mxx = fmaxf(mxx, x);
        mny = fminf(mny, y); mxy = fmaxf(mxy, y);
    }
    float ix = 1.f / (mxx - mnx + 1e-6f);
    float iy = 1.f / (mxy - mny + 1e-6f);

    do_level_f<0, 5, 4>(w, lane, W0, b0, mnx, ix, mny, iy, Praw, featS, WW, beS, finS);
    do_level_f<1, 4, 9>(w, lane, W1, b1, mnx, ix, mny, iy, Praw, featS, WW, beS, finS);
    do_level_f<2, 4, 4>(w, lane, W2, b2, mnx, ix, mny, iy, Praw, featS, WW, beS, finS);
    __syncthreads();

    float acc0 = bp[lane];
    float acc1 = bp[64 + lane];
    const float* r0 = Wp + (size_t)lane * 384;
    const float* r1 = Wp + (size_t)(64 + lane) * 384;
    const float* fv = finS[w];
#pragma unroll 8
    for (int e = 0; e < 384; e += 4) {
        float4 wa = *(const float4*)(r0 + e);
        float4 wb = *(const float4*)(r1 + e);
        float4 f = *(const float4*)(fv + e);
        acc0 = fmaf(wa.x, f.x, acc0);
        acc0 = fmaf(wa.y, f.y, acc0);
        acc0 = fmaf(wa.z, f.z, acc0);
        acc0 = fmaf(wa.w, f.w, acc0);
        acc1 = fmaf(wb.x, f.x, acc1);
        acc1 = fmaf(wb.y, f.y, acc1);
        acc1 = fmaf(wb.z, f.z, acc1);
        acc1 = fmaf(wb.w, f.w, acc1);
    }
    out[(size_t)sample * 128 + lane] = acc0;
    out[(size_t)sample * 128 + 64 + lane] = acc1;
}

extern "C" void kernel_launch(void* const* d_in, const int* in_sizes, int n_in,
                              void* d_out, int out_size, void* d_ws, size_t ws_size,
                              hipStream_t stream) {
    const float* kp = (const float*)d_in[0];
    const float* sc = (const float*)d_in[1];
    const float* W0 = (const float*)d_in[2];
    const float* b0 = (const float*)d_in[3];
    const float* W1 = (const float*)d_in[4];
    const float* b1 = (const float*)d_in[5];
    const float* W2 = (const float*)d_in[6];
    const float* b2 = (const float*)d_in[7];
    const float* We = (const float*)d_in[8];
    const float* be = (const float*)d_in[9];
    const float* Wp = (const float*)d_in[10];
    const float* bp = (const float*)d_in[11];
    float* out = (float*)d_out;

    int N = in_sizes[0] / 34;  // keypoints N*17*2 -> 8192
    size_t need = (size_t)N * 384 * sizeof(float);

    if (ws_size >= need) {
        float* fbuf = (float*)d_ws;
        hipLaunchKernelGGL(graph_kernel, dim3(N / 8), dim3(512), 0, stream,
                           kp, sc, W0, b0, W1, b1, W2, b2, We, be, fbuf);
        hipLaunchKernelGGL(out_gemm_kernel, dim3(N / 32), dim3(512), 0, stream,
                           fbuf, Wp, bp, out);
    } else {
        hipLaunchKernelGGL(hse_fused_kernel, dim3(N / 4), dim3(256), 0, stream,
                           kp, sc, W0, b0, W1, b1, W2, b2, We, be, Wp, bp, out);
    }
}

// Round 4
// 48.789 us; speedup vs baseline: 4.1530x; 1.4911x over previous
//
#include <hip/hip_runtime.h>
#include <hip/hip_bf16.h>

#define DEVINL __device__ __forceinline__

using bf16 = __hip_bfloat16;
typedef __attribute__((ext_vector_type(8))) short short8v;
typedef __attribute__((ext_vector_type(4))) float float4v;

// ===========================================================================
// K1: per-sample graph encoder (validated round 3). 8 waves/block, 1
// sample/wave. Writes final[sample][384] features to workspace as bf16.
// ===========================================================================

template <int LI, int CNT, int OTH>
DEVINL void do_level(int w, int lane,
                     const float* __restrict__ Wl, const float* __restrict__ bl,
                     float mnx, float ix, float mny, float iy,
                     const float (*Praw)[17][3],
                     float (*featS)[64][8],
                     const float2 (*WW)[64],
                     const float* beS,
                     bf16* __restrict__ outv) {
    constexpr int SUBJ[3][5] = {{0, 5, 6, 11, 12}, {7, 8, 13, 14, 16}, {9, 10, 15, 16, 16}};

    float w0 = Wl[lane * 3 + 0];
    float w1 = Wl[lane * 3 + 1];
    float w2 = Wl[lane * 3 + 2];
    float bb = bl[lane];

    float mj[CNT], sj[CNT];
    float msum = 0.f;
#pragma unroll
    for (int jj = 0; jj < CNT; ++jj) {
        int j = SUBJ[LI][jj];
        float px = (Praw[w][j][0] - mnx) * ix;
        float py = (Praw[w][j][1] - mny) * iy;
        float ps = Praw[w][j][2];
        float h = fmaxf(px * w0 + py * w1 + ps * w2 + bb, 0.f);
        float m = h * ps;
        mj[jj] = m;
        sj[jj] = ps;
        msum += m;
    }
#pragma unroll
    for (int jj = 0; jj < CNT; ++jj) {
        featS[w][lane][jj] = (msum - mj[jj]) * sj[jj];
    }
    float Hsum = (float)(CNT - 1) * msum;
    __syncthreads();

    // a_j[t] = (We1-We2)·feat_j + be ; c_j[t] = We2·feat_j  (t = lane)
    float a_[CNT], c_[CNT];
    float bet = beS[lane];
#pragma unroll
    for (int jj = 0; jj < CNT; ++jj) { a_[jj] = bet; c_[jj] = 0.f; }
#pragma unroll 4
    for (int d = 0; d < 64; ++d) {
        float2 wv = WW[d][lane ^ d];                  // XOR-swizzled columns
        const float* fr = &featS[w][d][0];            // broadcast reads
        float4 f4 = *(const float4*)fr;
        float f[5];
        f[0] = f4.x; f[1] = f4.y; f[2] = f4.z; f[3] = f4.w; f[4] = 0.f;
        if constexpr (CNT > 4) f[4] = fr[4];
#pragma unroll
        for (int jj = 0; jj < CNT; ++jj) {
            a_[jj] = fmaf(wv.x, f[jj], a_[jj]);
            c_[jj] = fmaf(wv.y, f[jj], c_[jj]);
        }
    }
    __syncthreads();

    float zsum = 0.f;
#pragma unroll
    for (int jj = 0; jj < CNT; ++jj) {
        float z = fmaxf(a_[jj], 0.f);
#pragma unroll
        for (int kk = 0; kk < CNT; ++kk) {
            if (kk != jj) z = fmaxf(z, a_[jj] + c_[kk]);
        }
        zsum += z;
    }
    float zo = 0.f;
#pragma unroll
    for (int kk = 0; kk < CNT; ++kk) zo = fmaxf(zo, bet + c_[kk]);
    zsum += (float)OTH * zo;

    outv[LI * 128 + lane] = __float2bfloat16(Hsum * (1.f / 17.f));
    outv[LI * 128 + 64 + lane] = __float2bfloat16(zsum * (1.f / 17.f));
}

__global__ __launch_bounds__(512, 6) void graph_kernel(
    const float* __restrict__ kp, const float* __restrict__ sc,
    const float* __restrict__ W0, const float* __restrict__ b0,
    const float* __restrict__ W1, const float* __restrict__ b1,
    const float* __restrict__ W2, const float* __restrict__ b2,
    const float* __restrict__ We, const float* __restrict__ be,
    bf16* __restrict__ fout) {
    __shared__ float2 WW[64][64];      // [d][t^d] = {We1-We2, We2}
    __shared__ float beS[64];
    __shared__ float Praw[8][17][3];
    __shared__ float featS[8][64][8];

    int tid = threadIdx.x;
    int w = tid >> 6;
    int lane = tid & 63;
    int sample = blockIdx.x * 8 + w;

    for (int i = tid; i < 4096; i += 512) {
        int t = i >> 6, d = i & 63;
        float wA = We[t * 128 + d];
        float wB = We[t * 128 + 64 + d];
        WW[d][t ^ d] = make_float2(wA - wB, wB);
    }
    if (tid < 64) beS[tid] = be[tid];

    if (lane < 17) {
        size_t base = (size_t)sample * 17 + lane;
        float2 xy = *(const float2*)(kp + base * 2);
        Praw[w][lane][0] = xy.x;
        Praw[w][lane][1] = xy.y;
        Praw[w][lane][2] = sc[base];
    }
    __syncthreads();

    int j = lane & 31;
    float xx = 0.f, yy = 0.f;
    if (j < 17) { xx = Praw[w][j][0]; yy = Praw[w][j][1]; }
    float mnx = (j < 17) ? xx : 1e30f, mxx = (j < 17) ? xx : -1e30f;
    float mny = (j < 17) ? yy : 1e30f, mxy = (j < 17) ? yy : -1e30f;
#pragma unroll
    for (int off = 16; off; off >>= 1) {
        mnx = fminf(mnx, __shfl_xor(mnx, off, 32));
        mxx = fmaxf(mxx, __shfl_xor(mxx, off, 32));
        mny = fminf(mny, __shfl_xor(mny, off, 32));
        mxy = fmaxf(mxy, __shfl_xor(mxy, off, 32));
    }
    float ix = 1.f / (mxx - mnx + 1e-6f);
    float iy = 1.f / (mxy - mny + 1e-6f);

    bf16* outv = fout + (size_t)sample * 384;
    do_level<0, 5, 4>(w, lane, W0, b0, mnx, ix, mny, iy, Praw, featS, WW, beS, outv);
    do_level<1, 4, 9>(w, lane, W1, b1, mnx, ix, mny, iy, Praw, featS, WW, beS, outv);
    do_level<2, 4, 4>(w, lane, W2, b2, mnx, ix, mny, iy, Praw, featS, WW, beS, outv);
}

// ===========================================================================
// K2: out[8192][128] = fin(bf16)[8192][384] @ Wp^T + bp via MFMA 16x16x32.
// 256 threads = 4 waves; BM = 64 samples (16/wave), BN = 128 (all outputs).
// Whole Wp converted to bf16 in LDS once (pad 392 => conflict-free b128
// fragment reads). A-fragments straight from global (16B/lane, L2-hot).
// Verified m89 layouts: A/B lane: row/col = l&15, k = (l>>4)*8+j;
// C: row = (l>>4)*4+reg, col = l&15.
// ===========================================================================
__global__ __launch_bounds__(256) void out_mfma_kernel(
    const bf16* __restrict__ fin, const float* __restrict__ Wp,
    const float* __restrict__ bp, float* __restrict__ out) {
    __shared__ unsigned short Bs[128][392];  // [o][k] bf16 bits, +8 pad
    __shared__ float bpS[128];

    int tid = threadIdx.x;
    int w = tid >> 6;
    int lane = tid & 63;

    // ---- stage Wp -> bf16 LDS (once) ----
    const float4* Wp4 = (const float4*)Wp;
    for (int f = tid; f < 12288; f += 256) {
        int o = f / 96;
        int k4 = f - o * 96;
        float4 v = Wp4[f];
        union { unsigned short u[4]; short s4[4]; } pk;
        pk.u[0] = __bfloat16_as_ushort(__float2bfloat16(v.x));
        pk.u[1] = __bfloat16_as_ushort(__float2bfloat16(v.y));
        pk.u[2] = __bfloat16_as_ushort(__float2bfloat16(v.z));
        pk.u[3] = __bfloat16_as_ushort(__float2bfloat16(v.w));
        *(uint2*)&Bs[o][k4 * 4] = *(uint2*)pk.u;
    }
    if (tid < 128) bpS[tid] = bp[tid];
    __syncthreads();

    // ---- MFMA main: 12 k-steps x 8 n-tiles ----
    int srow = blockIdx.x * 64 + w * 16 + (lane & 15);
    int kgrp = (lane >> 4) * 8;
    const short8v* aptr = (const short8v*)(fin + (size_t)srow * 384 + kgrp);

    float4v acc[8];
#pragma unroll
    for (int n = 0; n < 8; ++n) acc[n] = (float4v){0.f, 0.f, 0.f, 0.f};

    short8v a_cur = aptr[0];  // aptr steps in units of 8 elems; kt*32 -> +4
#pragma unroll
    for (int kt = 0; kt < 12; ++kt) {
        short8v a_nxt;
        if (kt < 11) a_nxt = aptr[(kt + 1) * 4];
#pragma unroll
        for (int n = 0; n < 8; ++n) {
            short8v b = *(const short8v*)&Bs[n * 16 + (lane & 15)][kt * 32 + kgrp];
            acc[n] = __builtin_amdgcn_mfma_f32_16x16x32_bf16(a_cur, b, acc[n], 0, 0, 0);
        }
        a_cur = a_nxt;
    }

    // ---- epilogue: add bias, store fp32 ----
    int orow = blockIdx.x * 64 + w * 16 + (lane >> 4) * 4;
    int ocol = lane & 15;
#pragma unroll
    for (int n = 0; n < 8; ++n) {
        float bv = bpS[n * 16 + ocol];
#pragma unroll
        for (int r = 0; r < 4; ++r) {
            out[(size_t)(orow + r) * 128 + n * 16 + ocol] = acc[n][r] + bv;
        }
    }
}

// ===========================================================================
// Fallback: validated round-2 fused kernel (used only if ws too small).
// ===========================================================================
template <int LI, int CNT, int OTH>
DEVINL void do_level_f(int w, int lane,
                       const float* __restrict__ Wl, const float* __restrict__ bl,
                       float mnx, float ix, float mny, float iy,
                       const float (*Praw)[17][3],
                       float (*featS)[64][8],
                       const float2 (*WW)[64],
                       const float* beS,
                       float (*finS)[384]) {
    constexpr int SUBJ[3][5] = {{0, 5, 6, 11, 12}, {7, 8, 13, 14, 16}, {9, 10, 15, 16, 16}};
    float w0 = Wl[lane * 3 + 0], w1 = Wl[lane * 3 + 1], w2 = Wl[lane * 3 + 2], bb = bl[lane];
    float mj[CNT], sj[CNT];
    float msum = 0.f;
#pragma unroll
    for (int jj = 0; jj < CNT; ++jj) {
        int j = SUBJ[LI][jj];
        float px = (Praw[w][j][0] - mnx) * ix;
        float py = (Praw[w][j][1] - mny) * iy;
        float ps = Praw[w][j][2];
        float h = fmaxf(px * w0 + py * w1 + ps * w2 + bb, 0.f);
        float m = h * ps;
        mj[jj] = m; sj[jj] = ps; msum += m;
    }
#pragma unroll
    for (int jj = 0; jj < CNT; ++jj) featS[w][lane][jj] = (msum - mj[jj]) * sj[jj];
    float Hsum = (float)(CNT - 1) * msum;
    __syncthreads();
    float a_[CNT], c_[CNT];
    float bet = beS[lane];
#pragma unroll
    for (int jj = 0; jj < CNT; ++jj) { a_[jj] = bet; c_[jj] = 0.f; }
#pragma unroll 4
    for (int d = 0; d < 64; ++d) {
        float2 wv = WW[d][lane];
        const float* fr = &featS[w][d][0];
        float4 f4 = *(const float4*)fr;
        float f[5];
        f[0] = f4.x; f[1] = f4.y; f[2] = f4.z; f[3] = f4.w; f[4] = 0.f;
        if constexpr (CNT > 4) f[4] = fr[4];
#pragma unroll
        for (int jj = 0; jj < CNT; ++jj) {
            a_[jj] = fmaf(wv.x, f[jj], a_[jj]);
            c_[jj] = fmaf(wv.y, f[jj], c_[jj]);
        }
    }
    __syncthreads();
    float zsum = 0.f;
#pragma unroll
    for (int jj = 0; jj < CNT; ++jj) {
        float z = fmaxf(a_[jj], 0.f);
#pragma unroll
        for (int kk = 0; kk < CNT; ++kk)
            if (kk != jj) z = fmaxf(z, a_[jj] + c_[kk]);
        zsum += z;
    }
    float zo = 0.f;
#pragma unroll
    for (int kk = 0; kk < CNT; ++kk) zo = fmaxf(zo, bet + c_[kk]);
    zsum += (float)OTH * zo;
    finS[w][LI * 128 + lane] = Hsum * (1.f / 17.f);
    finS[w][LI * 128 + 64 + lane] = zsum * (1.f / 17.f);
}

__global__ __launch_bounds__(256) void hse_fused_kernel(
    const float* __restrict__ kp, const float* __restrict__ sc,
    const float* __restrict__ W0, const float* __restrict__ b0,
    const float* __restrict__ W1, const float* __restrict__ b1,
    const float* __restrict__ W2, const float* __restrict__ b2,
    const float* __restrict__ We, const float* __restrict__ be,
    const float* __restrict__ Wp, const float* __restrict__ bp,
    float* __restrict__ out) {
    __shared__ float2 WW[64][64];
    __shared__ float beS[64];
    __shared__ float Praw[4][17][3];
    __shared__ float featS[4][64][8];
    __shared__ float finS[4][384];

    int tid = threadIdx.x;
    int w = tid >> 6;
    int lane = tid & 63;
    int sample = blockIdx.x * 4 + w;

    for (int i = tid; i < 4096; i += 256) {
        int t = i >> 6, d = i & 63;
        float wA = We[t * 128 + d];
        float wB = We[t * 128 + 64 + d];
        WW[d][t] = make_float2(wA - wB, wB);
    }
    if (tid < 64) beS[tid] = be[tid];
    if (lane < 17) {
        size_t base = (size_t)sample * 17 + lane;
        float2 xy = *(const float2*)(kp + base * 2);
        Praw[w][lane][0] = xy.x;
        Praw[w][lane][1] = xy.y;
        Praw[w][lane][2] = sc[base];
    }
    __syncthreads();

    float mnx = 1e30f, mxx = -1e30f, mny = 1e30f, mxy = -1e30f;
    for (int j = 0; j < 17; ++j) {
        float x = Praw[w][j][0], y = Praw[w][j][1];
        mnx = fminf(mnx, x); mxx = fmaxf(mxx, x);
        mny = fminf(mny, y); mxy = fmaxf(mxy, y);
    }
    float ix = 1.f / (mxx - mnx + 1e-6f);
    float iy = 1.f / (mxy - mny + 1e-6f);

    do_level_f<0, 5, 4>(w, lane, W0, b0, mnx, ix, mny, iy, Praw, featS, WW, beS, finS);
    do_level_f<1, 4, 9>(w, lane, W1, b1, mnx, ix, mny, iy, Praw, featS, WW, beS, finS);
    do_level_f<2, 4, 4>(w, lane, W2, b2, mnx, ix, mny, iy, Praw, featS, WW, beS, finS);
    __syncthreads();

    float acc0 = bp[lane];
    float acc1 = bp[64 + lane];
    const float* r0 = Wp + (size_t)lane * 384;
    const float* r1 = Wp + (size_t)(64 + lane) * 384;
    const float* fv = finS[w];
#pragma unroll 8
    for (int e = 0; e < 384; e += 4) {
        float4 wa = *(const float4*)(r0 + e);
        float4 wb = *(const float4*)(r1 + e);
        float4 f = *(const float4*)(fv + e);
        acc0 = fmaf(wa.x, f.x, acc0);
        acc0 = fmaf(wa.y, f.y, acc0);
        acc0 = fmaf(wa.z, f.z, acc0);
        acc0 = fmaf(wa.w, f.w, acc0);
        acc1 = fmaf(wb.x, f.x, acc1);
        acc1 = fmaf(wb.y, f.y, acc1);
        acc1 = fmaf(wb.z, f.z, acc1);
        acc1 = fmaf(wb.w, f.w, acc1);
    }
    out[(size_t)sample * 128 + lane] = acc0;
    out[(size_t)sample * 128 + 64 + lane] = acc1;
}

extern "C" void kernel_launch(void* const* d_in, const int* in_sizes, int n_in,
                              void* d_out, int out_size, void* d_ws, size_t ws_size,
                              hipStream_t stream) {
    const float* kp = (const float*)d_in[0];
    const float* sc = (const float*)d_in[1];
    const float* W0 = (const float*)d_in[2];
    const float* b0 = (const float*)d_in[3];
    const float* W1 = (const float*)d_in[4];
    const float* b1 = (const float*)d_in[5];
    const float* W2 = (const float*)d_in[6];
    const float* b2 = (const float*)d_in[7];
    const float* We = (const float*)d_in[8];
    const float* be = (const float*)d_in[9];
    const float* Wp = (const float*)d_in[10];
    const float* bp = (const float*)d_in[11];
    float* out = (float*)d_out;

    int N = in_sizes[0] / 34;  // keypoints N*17*2 -> 8192
    size_t need = (size_t)N * 384 * sizeof(bf16);

    if (ws_size >= need) {
        bf16* fbuf = (bf16*)d_ws;
        hipLaunchKernelGGL(graph_kernel, dim3(N / 8), dim3(512), 0, stream,
                           kp, sc, W0, b0, W1, b1, W2, b2, We, be, fbuf);
        hipLaunchKernelGGL(out_mfma_kernel, dim3(N / 64), dim3(256), 0, stream,
                           fbuf, Wp, bp, out);
    } else {
        hipLaunchKernelGGL(hse_fused_kernel, dim3(N / 4), dim3(256), 0, stream,
                           kp, sc, W0, b0, W1, b1, W2, b2, We, be, Wp, bp, out);
    }
}

// Round 5
// 48.352 us; speedup vs baseline: 4.1905x; 1.0090x over previous
//
#include <hip/hip_runtime.h>
#include <hip/hip_bf16.h>

#define DEVINL __device__ __forceinline__

using bf16 = __hip_bfloat16;
typedef __attribute__((ext_vector_type(8))) short short8v;
typedef __attribute__((ext_vector_type(4))) float float4v;
typedef __attribute__((ext_vector_type(2))) float f32x2;

// ===========================================================================
// K1: per-sample graph encoder. 8 waves/block, 1 sample/wave. Writes
// final[sample][384] features to workspace as bf16. Also converts Wp -> bf16
// into workspace (first 12288 global threads, one float4 each) so K2 needs
// no conversion and no LDS.
//
// Algebra (validated rounds 2-4): PHYS = complete graph per subset =>
// H_u = msum - m_u; edge MLP msg = relu(a_j + c_k), a_j = (We1-We2)·feat_j+be,
// c_k = We2·feat_k; feat==0 off-subset => cross-level c==0, other-side a==be;
// OTH adjacent other-side joints share Zoth = max_k relu(be + c_k).
// ===========================================================================

template <int LI, int CNT, int OTH>
DEVINL void do_level(int w, int lane,
                     const float* __restrict__ Wl, const float* __restrict__ bl,
                     float mnx, float ix, float mny, float iy,
                     const float (*Praw)[17][3],
                     float (*featS)[64][8],
                     const float2 (*WW)[64],
                     const float* beS,
                     bf16* __restrict__ outv) {
    constexpr int SUBJ[3][5] = {{0, 5, 6, 11, 12}, {7, 8, 13, 14, 16}, {9, 10, 15, 16, 16}};

    float w0 = Wl[lane * 3 + 0];
    float w1 = Wl[lane * 3 + 1];
    float w2 = Wl[lane * 3 + 2];
    float bb = bl[lane];

    float mj[CNT], sj[CNT];
    float msum = 0.f;
#pragma unroll
    for (int jj = 0; jj < CNT; ++jj) {
        int j = SUBJ[LI][jj];
        float px = (Praw[w][j][0] - mnx) * ix;
        float py = (Praw[w][j][1] - mny) * iy;
        float ps = Praw[w][j][2];
        float h = fmaxf(px * w0 + py * w1 + ps * w2 + bb, 0.f);
        float m = h * ps;
        mj[jj] = m;
        sj[jj] = ps;
        msum += m;
    }
#pragma unroll
    for (int jj = 0; jj < CNT; ++jj) {
        featS[w][lane][jj] = (msum - mj[jj]) * sj[jj];
    }
    float Hsum = (float)(CNT - 1) * msum;
    __syncthreads();

    // acp[jj] = {a_j[t], c_j[t]} accumulated with packed fp32 FMA
    f32x2 acp[CNT];
    float bet = beS[lane];
#pragma unroll
    for (int jj = 0; jj < CNT; ++jj) acp[jj] = (f32x2){bet, 0.f};
#pragma unroll 4
    for (int d = 0; d < 64; ++d) {
        float2 wv = WW[d][lane ^ d];                  // XOR-swizzled columns
        f32x2 wvv = {wv.x, wv.y};
        const float* fr = &featS[w][d][0];            // broadcast reads
        float4 f4 = *(const float4*)fr;
        float f[5];
        f[0] = f4.x; f[1] = f4.y; f[2] = f4.z; f[3] = f4.w; f[4] = 0.f;
        if constexpr (CNT > 4) f[4] = fr[4];
#pragma unroll
        for (int jj = 0; jj < CNT; ++jj) {
            acp[jj] += wvv * (f32x2){f[jj], f[jj]};   // v_pk_fma_f32
        }
    }
    __syncthreads();

    float a_[CNT], c_[CNT];
#pragma unroll
    for (int jj = 0; jj < CNT; ++jj) { a_[jj] = acp[jj].x; c_[jj] = acp[jj].y; }

    float zsum = 0.f;
#pragma unroll
    for (int jj = 0; jj < CNT; ++jj) {
        float z = fmaxf(a_[jj], 0.f);
#pragma unroll
        for (int kk = 0; kk < CNT; ++kk) {
            if (kk != jj) z = fmaxf(z, a_[jj] + c_[kk]);
        }
        zsum += z;
    }
    float zo = 0.f;
#pragma unroll
    for (int kk = 0; kk < CNT; ++kk) zo = fmaxf(zo, bet + c_[kk]);
    zsum += (float)OTH * zo;

    outv[LI * 128 + lane] = __float2bfloat16(Hsum * (1.f / 17.f));
    outv[LI * 128 + 64 + lane] = __float2bfloat16(zsum * (1.f / 17.f));
}

__global__ __launch_bounds__(512, 6) void graph_kernel(
    const float* __restrict__ kp, const float* __restrict__ sc,
    const float* __restrict__ W0, const float* __restrict__ b0,
    const float* __restrict__ W1, const float* __restrict__ b1,
    const float* __restrict__ W2, const float* __restrict__ b2,
    const float* __restrict__ We, const float* __restrict__ be,
    const float* __restrict__ Wp, unsigned short* __restrict__ wpB,
    bf16* __restrict__ fout) {
    __shared__ float2 WW[64][64];      // [d][t^d] = {We1-We2, We2}
    __shared__ float beS[64];
    __shared__ float Praw[8][17][3];
    __shared__ float featS[8][64][8];

    int tid = threadIdx.x;
    int w = tid >> 6;
    int lane = tid & 63;
    int sample = blockIdx.x * 8 + w;

    // ---- Wp -> bf16 conversion (first 12288 global threads, 1 float4 each)
    int gid = blockIdx.x * 512 + tid;
    if (gid < 12288) {
        float4 v = ((const float4*)Wp)[gid];
        union { unsigned short u[4]; uint2 d2; } pk;
        pk.u[0] = __bfloat16_as_ushort(__float2bfloat16(v.x));
        pk.u[1] = __bfloat16_as_ushort(__float2bfloat16(v.y));
        pk.u[2] = __bfloat16_as_ushort(__float2bfloat16(v.z));
        pk.u[3] = __bfloat16_as_ushort(__float2bfloat16(v.w));
        *(uint2*)&wpB[gid * 4] = pk.d2;
    }

    for (int i = tid; i < 4096; i += 512) {
        int t = i >> 6, d = i & 63;
        float wA = We[t * 128 + d];
        float wB = We[t * 128 + 64 + d];
        WW[d][t ^ d] = make_float2(wA - wB, wB);
    }
    if (tid < 64) beS[tid] = be[tid];

    if (lane < 17) {
        size_t base = (size_t)sample * 17 + lane;
        float2 xy = *(const float2*)(kp + base * 2);
        Praw[w][lane][0] = xy.x;
        Praw[w][lane][1] = xy.y;
        Praw[w][lane][2] = sc[base];
    }
    __syncthreads();

    int j = lane & 31;
    float xx = 0.f, yy = 0.f;
    if (j < 17) { xx = Praw[w][j][0]; yy = Praw[w][j][1]; }
    float mnx = (j < 17) ? xx : 1e30f, mxx = (j < 17) ? xx : -1e30f;
    float mny = (j < 17) ? yy : 1e30f, mxy = (j < 17) ? yy : -1e30f;
#pragma unroll
    for (int off = 16; off; off >>= 1) {
        mnx = fminf(mnx, __shfl_xor(mnx, off, 32));
        mxx = fmaxf(mxx, __shfl_xor(mxx, off, 32));
        mny = fminf(mny, __shfl_xor(mny, off, 32));
        mxy = fmaxf(mxy, __shfl_xor(mxy, off, 32));
    }
    float ix = 1.f / (mxx - mnx + 1e-6f);
    float iy = 1.f / (mxy - mny + 1e-6f);

    bf16* outv = fout + (size_t)sample * 384;
    do_level<0, 5, 4>(w, lane, W0, b0, mnx, ix, mny, iy, Praw, featS, WW, beS, outv);
    do_level<1, 4, 9>(w, lane, W1, b1, mnx, ix, mny, iy, Praw, featS, WW, beS, outv);
    do_level<2, 4, 4>(w, lane, W2, b2, mnx, ix, mny, iy, Praw, featS, WW, beS, outv);
}

// ===========================================================================
// K2: out[8192][128] = fin(bf16)[8192][384] @ WpB^T + bp via MFMA 16x16x32.
// NO LDS, NO barriers. 512 blocks x 4 waves; block = one 16-sample m-tile;
// wave w = n-tiles {2w, 2w+1}. Per wave: 12 A-loads + 24 B-loads (16B, all
// L2-hot) + 24 MFMA. Layouts (m89-verified, validated round 4):
// A/B: row/col = l&15, k = (l>>4)*8+j;  C: row = (l>>4)*4+reg, col = l&15.
// ===========================================================================
__global__ __launch_bounds__(256) void out_mfma_kernel(
    const bf16* __restrict__ fin, const unsigned short* __restrict__ wpB,
    const float* __restrict__ bp, float* __restrict__ out) {
    int tid = threadIdx.x;
    int w = tid >> 6;
    int lane = tid & 63;
    int m0 = blockIdx.x * 16;
    int r16 = lane & 15;
    int kg = (lane >> 4) * 8;

    const short8v* aptr = (const short8v*)(fin + (size_t)(m0 + r16) * 384 + kg);
    int n0 = 2 * w, n1 = 2 * w + 1;
    const short8v* bptr0 = (const short8v*)(wpB + (size_t)(n0 * 16 + r16) * 384 + kg);
    const short8v* bptr1 = (const short8v*)(wpB + (size_t)(n1 * 16 + r16) * 384 + kg);

    float4v acc0 = (float4v){0.f, 0.f, 0.f, 0.f};
    float4v acc1 = (float4v){0.f, 0.f, 0.f, 0.f};
#pragma unroll
    for (int kt = 0; kt < 12; ++kt) {
        short8v a = aptr[kt * 4];    // +32 elems per kt
        short8v b0 = bptr0[kt * 4];
        short8v b1 = bptr1[kt * 4];
        acc0 = __builtin_amdgcn_mfma_f32_16x16x32_bf16(a, b0, acc0, 0, 0, 0);
        acc1 = __builtin_amdgcn_mfma_f32_16x16x32_bf16(a, b1, acc1, 0, 0, 0);
    }

    int orow = m0 + (lane >> 4) * 4;
    float bv0 = bp[n0 * 16 + r16];
    float bv1 = bp[n1 * 16 + r16];
#pragma unroll
    for (int r = 0; r < 4; ++r) {
        out[(size_t)(orow + r) * 128 + n0 * 16 + r16] = acc0[r] + bv0;
        out[(size_t)(orow + r) * 128 + n1 * 16 + r16] = acc1[r] + bv1;
    }
}

// ===========================================================================
// Fallback: validated round-2 fused kernel (used only if ws too small).
// ===========================================================================
template <int LI, int CNT, int OTH>
DEVINL void do_level_f(int w, int lane,
                       const float* __restrict__ Wl, const float* __restrict__ bl,
                       float mnx, float ix, float mny, float iy,
                       const float (*Praw)[17][3],
                       float (*featS)[64][8],
                       const float2 (*WW)[64],
                       const float* beS,
                       float (*finS)[384]) {
    constexpr int SUBJ[3][5] = {{0, 5, 6, 11, 12}, {7, 8, 13, 14, 16}, {9, 10, 15, 16, 16}};
    float w0 = Wl[lane * 3 + 0], w1 = Wl[lane * 3 + 1], w2 = Wl[lane * 3 + 2], bb = bl[lane];
    float mj[CNT], sj[CNT];
    float msum = 0.f;
#pragma unroll
    for (int jj = 0; jj < CNT; ++jj) {
        int j = SUBJ[LI][jj];
        float px = (Praw[w][j][0] - mnx) * ix;
        float py = (Praw[w][j][1] - mny) * iy;
        float ps = Praw[w][j][2];
        float h = fmaxf(px * w0 + py * w1 + ps * w2 + bb, 0.f);
        float m = h * ps;
        mj[jj] = m; sj[jj] = ps; msum += m;
    }
#pragma unroll
    for (int jj = 0; jj < CNT; ++jj) featS[w][lane][jj] = (msum - mj[jj]) * sj[jj];
    float Hsum = (float)(CNT - 1) * msum;
    __syncthreads();
    float a_[CNT], c_[CNT];
    float bet = beS[lane];
#pragma unroll
    for (int jj = 0; jj < CNT; ++jj) { a_[jj] = bet; c_[jj] = 0.f; }
#pragma unroll 4
    for (int d = 0; d < 64; ++d) {
        float2 wv = WW[d][lane];
        const float* fr = &featS[w][d][0];
        float4 f4 = *(const float4*)fr;
        float f[5];
        f[0] = f4.x; f[1] = f4.y; f[2] = f4.z; f[3] = f4.w; f[4] = 0.f;
        if constexpr (CNT > 4) f[4] = fr[4];
#pragma unroll
        for (int jj = 0; jj < CNT; ++jj) {
            a_[jj] = fmaf(wv.x, f[jj], a_[jj]);
            c_[jj] = fmaf(wv.y, f[jj], c_[jj]);
        }
    }
    __syncthreads();
    float zsum = 0.f;
#pragma unroll
    for (int jj = 0; jj < CNT; ++jj) {
        float z = fmaxf(a_[jj], 0.f);
#pragma unroll
        for (int kk = 0; kk < CNT; ++kk)
            if (kk != jj) z = fmaxf(z, a_[jj] + c_[kk]);
        zsum += z;
    }
    float zo = 0.f;
#pragma unroll
    for (int kk = 0; kk < CNT; ++kk) zo = fmaxf(zo, bet + c_[kk]);
    zsum += (float)OTH * zo;
    finS[w][LI * 128 + lane] = Hsum * (1.f / 17.f);
    finS[w][LI * 128 + 64 + lane] = zsum * (1.f / 17.f);
}

__global__ __launch_bounds__(256) void hse_fused_kernel(
    const float* __restrict__ kp, const float* __restrict__ sc,
    const float* __restrict__ W0, const float* __restrict__ b0,
    const float* __restrict__ W1, const float* __restrict__ b1,
    const float* __restrict__ W2, const float* __restrict__ b2,
    const float* __restrict__ We, const float* __restrict__ be,
    const float* __restrict__ Wp, const float* __restrict__ bp,
    float* __restrict__ out) {
    __shared__ float2 WW[64][64];
    __shared__ float beS[64];
    __shared__ float Praw[4][17][3];
    __shared__ float featS[4][64][8];
    __shared__ float finS[4][384];

    int tid = threadIdx.x;
    int w = tid >> 6;
    int lane = tid & 63;
    int sample = blockIdx.x * 4 + w;

    for (int i = tid; i < 4096; i += 256) {
        int t = i >> 6, d = i & 63;
        float wA = We[t * 128 + d];
        float wB = We[t * 128 + 64 + d];
        WW[d][t] = make_float2(wA - wB, wB);
    }
    if (tid < 64) beS[tid] = be[tid];
    if (lane < 17) {
        size_t base = (size_t)sample * 17 + lane;
        float2 xy = *(const float2*)(kp + base * 2);
        Praw[w][lane][0] = xy.x;
        Praw[w][lane][1] = xy.y;
        Praw[w][lane][2] = sc[base];
    }
    __syncthreads();

    float mnx = 1e30f, mxx = -1e30f, mny = 1e30f, mxy = -1e30f;
    for (int j = 0; j < 17; ++j) {
        float x = Praw[w][j][0], y = Praw[w][j][1];
        mnx = fminf(mnx, x); mxx = fmaxf(mxx, x);
        mny = fminf(mny, y); mxy = fmaxf(mxy, y);
    }
    float ix = 1.f / (mxx - mnx + 1e-6f);
    float iy = 1.f / (mxy - mny + 1e-6f);

    do_level_f<0, 5, 4>(w, lane, W0, b0, mnx, ix, mny, iy, Praw, featS, WW, beS, finS);
    do_level_f<1, 4, 9>(w, lane, W1, b1, mnx, ix, mny, iy, Praw, featS, WW, beS, finS);
    do_level_f<2, 4, 4>(w, lane, W2, b2, mnx, ix, mny, iy, Praw, featS, WW, beS, finS);
    __syncthreads();

    float acc0 = bp[lane];
    float acc1 = bp[64 + lane];
    const float* r0 = Wp + (size_t)lane * 384;
    const float* r1 = Wp + (size_t)(64 + lane) * 384;
    const float* fv = finS[w];
#pragma unroll 8
    for (int e = 0; e < 384; e += 4) {
        float4 wa = *(const float4*)(r0 + e);
        float4 wb = *(const float4*)(r1 + e);
        float4 f = *(const float4*)(fv + e);
        acc0 = fmaf(wa.x, f.x, acc0);
        acc0 = fmaf(wa.y, f.y, acc0);
        acc0 = fmaf(wa.z, f.z, acc0);
        acc0 = fmaf(wa.w, f.w, acc0);
        acc1 = fmaf(wb.x, f.x, acc1);
        acc1 = fmaf(wb.y, f.y, acc1);
        acc1 = fmaf(wb.z, f.z, acc1);
        acc1 = fmaf(wb.w, f.w, acc1);
    }
    out[(size_t)sample * 128 + lane] = acc0;
    out[(size_t)sample * 128 + 64 + lane] = acc1;
}

extern "C" void kernel_launch(void* const* d_in, const int* in_sizes, int n_in,
                              void* d_out, int out_size, void* d_ws, size_t ws_size,
                              hipStream_t stream) {
    const float* kp = (const float*)d_in[0];
    const float* sc = (const float*)d_in[1];
    const float* W0 = (const float*)d_in[2];
    const float* b0 = (const float*)d_in[3];
    const float* W1 = (const float*)d_in[4];
    const float* b1 = (const float*)d_in[5];
    const float* W2 = (const float*)d_in[6];
    const float* b2 = (const float*)d_in[7];
    const float* We = (const float*)d_in[8];
    const float* be = (const float*)d_in[9];
    const float* Wp = (const float*)d_in[10];
    const float* bp = (const float*)d_in[11];
    float* out = (float*)d_out;

    int N = in_sizes[0] / 34;  // keypoints N*17*2 -> 8192
    size_t finBytes = (size_t)N * 384 * sizeof(bf16);
    size_t need = finBytes + 49152 * sizeof(unsigned short);

    if (ws_size >= need) {
        bf16* fbuf = (bf16*)d_ws;
        unsigned short* wpB = (unsigned short*)((char*)d_ws + finBytes);
        hipLaunchKernelGGL(graph_kernel, dim3(N / 8), dim3(512), 0, stream,
                           kp, sc, W0, b0, W1, b1, W2, b2, We, be, Wp, wpB, fbuf);
        hipLaunchKernelGGL(out_mfma_kernel, dim3(N / 16), dim3(256), 0, stream,
                           fbuf, wpB, bp, out);
    } else {
        hipLaunchKernelGGL(hse_fused_kernel, dim3(N / 4), dim3(256), 0, stream,
                           kp, sc, W0, b0, W1, b1, W2, b2, We, be, Wp, bp, out);
    }
}